// Round 5
// baseline (4809.516 us; speedup 1.0000x reference)
//
#include <hip/hip_runtime.h>
#include <math.h>

#define L_SEQ 1024
#define WIN   32
#define CDIM  144
#define NW    993            // (1024-32)/1 + 1
#define HDIM  512
#define RDIM  256
#define M_ROWS (NW*CDIM)     // 142992
#define TILE_M 8
#define NBLK  (M_ROWS/TILE_M) // 17874
#define SLOPE 0.1

__device__ __forceinline__ double dlrelu(double x){ return x >= 0.0 ? x : SLOPE*x; }

// ---------------- prologue: axis-angle -> 6D (fp64 math) ----------------
__global__ void k_prep(const float* __restrict__ dp, float* __restrict__ d6){
  int idx = blockIdx.x*256 + threadIdx.x;
  if (idx >= L_SEQ*24) return;
  int l = idx / 24, j = idx % 24;
  const float* a = dp + l*72 + j*3;
  double x = (double)a[0], y = (double)a[1], z = (double)a[2];
  double ang = sqrt(x*x + y*y + z*z);
  double inv = 1.0 / fmax(ang, 1e-8);
  double ax = x*inv, ay = y*inv, az = z*inv;
  double s = sin(ang), c = cos(ang), C = 1.0 - c;
  float* o = d6 + l*CDIM + j*6;
  o[0] = (float)(c + ax*ax*C);
  o[1] = (float)(ax*ay*C - az*s);
  o[2] = (float)(ax*az*C + ay*s);
  o[3] = (float)(ay*ax*C + az*s);
  o[4] = (float)(c + ay*ay*C);
  o[5] = (float)(ay*az*C - ax*s);
}

// ---------------- weight prep: transpose + pair-interleave (fp32) ----------
// For W[J][K] row-major: dst[k*J + 2*(j%CS) + (j/CS)] = W[j][k], CS=J/2.
// A thread owning pair p then reads cols (p, p+CS) at k as ONE float2.
__global__ void k_wprep(const float* __restrict__ w_in, const float* __restrict__ w1a,
                        const float* __restrict__ w1b, const float* __restrict__ w2a,
                        const float* __restrict__ w2b, const float* __restrict__ w_out,
                        float* __restrict__ winP, float* __restrict__ w1aP,
                        float* __restrict__ w1bP, float* __restrict__ w2aP,
                        float* __restrict__ w2bP, float* __restrict__ woutP){
  int idx = blockIdx.x*256 + threadIdx.x;
  if (idx < 16384){                                   // w_in (512,32)
    int j = idx >> 5, k = idx & 31;
    winP[k*512 + 2*(j & 255) + (j >> 8)] = w_in[idx];
  } else if (idx < 147456){                           // w1a (256,512)
    int t = idx - 16384; int j = t >> 9, k = t & 511;
    w1aP[k*256 + 2*(j & 127) + (j >> 7)] = w1a[t];
  } else if (idx < 278528){                           // w1b (512,256)
    int t = idx - 147456; int j = t >> 8, k = t & 255;
    w1bP[k*512 + 2*(j & 255) + (j >> 8)] = w1b[t];
  } else if (idx < 409600){                           // w2a (256,512)
    int t = idx - 278528; int j = t >> 9, k = t & 511;
    w2aP[k*256 + 2*(j & 127) + (j >> 7)] = w2a[t];
  } else if (idx < 540672){                           // w2b (512,256)
    int t = idx - 409600; int j = t >> 8, k = t & 255;
    w2bP[k*512 + 2*(j & 255) + (j >> 8)] = w2b[t];
  } else if (idx < 557056){                           // w_out (32,512) -> [k][t]
    int t = idx - 540672; int j = t >> 9, k = t & 511;
    woutP[k*32 + j] = w_out[t];
  }
}

// ---------------- fused MLP ----------------
// Activations fp64 in LDS, [k][r] (r-stride 8) -> per-k reads are wave-uniform
// broadcast double2. Weights fp32 pair-interleaved; ONE float2 load + 2 cvt
// per k per thread, register double-buffered one k-group ahead (hides L2
// latency under the fma block). Numeric chains identical to the passing
// round-2/4 kernels (same per-element k-order fp64 fma; activations rounded
// through fp32 at each store; residual adds in fp32).
template<int KD, int JD, bool RES>
__device__ __forceinline__ void layerF(const double* S, double* D,
                                       const float* __restrict__ Wp,
                                       const float* __restrict__ bias, int tid){
  constexpr int CS = JD/2;
  constexpr int R  = (JD==512) ? 8 : 4;
  constexpr int G  = (JD==512) ? 4 : 8;   // prefetch group: ~256 fma cyc per group
  const int p     = (JD==512) ? tid : (tid & 127);
  const int rbase = (JD==512) ? 0   : ((tid >> 7) * 4);
  const float2* wp = (const float2*)Wp + p;   // stride CS float2 per k

  double acc0[R], acc1[R];
  #pragma unroll
  for (int r = 0; r < R; ++r){ acc0[r]=0.0; acc1[r]=0.0; }

  float2 wreg[G], wnxt[G];
  #pragma unroll
  for (int g = 0; g < G; ++g) wreg[g] = wp[(size_t)g*CS];

  for (int k0 = 0; k0 < KD; k0 += G){
    // prefetch next group (last-group overrun lands in the next ws array: safe)
    #pragma unroll
    for (int g = 0; g < G; ++g) wnxt[g] = wp[(size_t)(k0+G+g)*CS];
    #pragma unroll
    for (int g = 0; g < G; ++g){
      const int k = k0 + g;
      const double* sp = S + k*TILE_M + rbase;
      double w0 = (double)wreg[g].x, w1 = (double)wreg[g].y;
      #pragma unroll
      for (int i = 0; i < R; i += 2){
        double2 v = *(const double2*)(sp + i);
        acc0[i]   = fma(v.x, w0, acc0[i]);
        acc0[i+1] = fma(v.y, w0, acc0[i+1]);
        acc1[i]   = fma(v.x, w1, acc1[i]);
        acc1[i+1] = fma(v.y, w1, acc1[i+1]);
      }
    }
    #pragma unroll
    for (int g = 0; g < G; ++g) wreg[g] = wnxt[g];
  }

  double b0 = (double)bias[p], b1 = (double)bias[p + CS];
  double* d0 = D + (size_t)p*TILE_M + rbase;
  double* d1 = D + (size_t)(p+CS)*TILE_M + rbase;
  #pragma unroll
  for (int r = 0; r < R; ++r){
    float v0 = (float)dlrelu(acc0[r] + b0);
    float v1 = (float)dlrelu(acc1[r] + b1);
    if (RES){
      float h0 = (float)d0[r] + v0;   // fp32 residual add (matches reference chain)
      float h1 = (float)d1[r] + v1;
      d0[r] = (double)h0; d1[r] = (double)h1;
    } else {
      d0[r] = (double)v0; d1[r] = (double)v1;
    }
  }
}

__global__ __launch_bounds__(256, 3) void k_mlp(
    const float* __restrict__ d6,
    const float* __restrict__ winP, const float* __restrict__ b_in,
    const float* __restrict__ w1aP, const float* __restrict__ b1a,
    const float* __restrict__ w1bP, const float* __restrict__ b1b,
    const float* __restrict__ w2aP, const float* __restrict__ b2a,
    const float* __restrict__ w2bP, const float* __restrict__ b2b,
    const float* __restrict__ woutP, const float* __restrict__ b_out,
    float* __restrict__ y)
{
  __shared__ __align__(16) double hb[HDIM*TILE_M];   // 32 KiB, [k][r]
  __shared__ __align__(16) double rb[RDIM*TILE_M];   // 16 KiB, [k][r]; xb overlays
  const int tid = threadIdx.x;
  const int m0  = blockIdx.x * TILE_M;

  // gather input windows into xb (= rb[0..255]): xb[t*8 + r] = d6[(n+t)*144 + c]
  {
    int r = tid & 7, t = tid >> 3;       // t in 0..31
    int m = m0 + r;
    int n = m / CDIM, c = m % CDIM;
    rb[t*TILE_M + r] = (double)d6[(n+t)*CDIM + c];
  }
  __syncthreads();

  layerF<WIN , HDIM, false>(rb, hb, winP, b_in, tid);  __syncthreads();
  layerF<HDIM, RDIM, false>(hb, rb, w1aP, b1a, tid);  __syncthreads();
  layerF<RDIM, HDIM, true >(rb, hb, w1bP, b1b, tid);  __syncthreads();
  layerF<HDIM, RDIM, false>(hb, rb, w2aP, b2a, tid);  __syncthreads();
  layerF<RDIM, HDIM, true >(rb, hb, w2bP, b2b, tid);  __syncthreads();

  // ---- L_out: 512 -> 32, one (row, t) per thread; 4 partial fp64 sums ----
  {
    const int r  = tid & 7;
    const int th = tid >> 3;             // 0..31
    const float* wo = woutP + th;        // [k*32 + th]
    double s0=0.0, s1=0.0, s2=0.0, s3=0.0;
    #pragma unroll 2
    for (int k0 = 0; k0 < HDIM; k0 += 4){
      float w0 = wo[(k0+0)*32], w1 = wo[(k0+1)*32];
      float w2 = wo[(k0+2)*32], w3 = wo[(k0+3)*32];
      s0 = fma(hb[(k0+0)*TILE_M + r], (double)w0, s0);
      s1 = fma(hb[(k0+1)*TILE_M + r], (double)w1, s1);
      s2 = fma(hb[(k0+2)*TILE_M + r], (double)w2, s2);
      s3 = fma(hb[(k0+3)*TILE_M + r], (double)w3, s3);
    }
    double o = (s0 + s1) + (s2 + s3);
    int m = m0 + r;
    int n = m / CDIM, c = m % CDIM;
    y[(size_t)th*M_ROWS + n*CDIM + c] = (float)(o + (double)b_out[th]);
  }
}

// ---------------- overlap-average scatter (fp64 sum) ----------------
__global__ void k_scatter(const float* __restrict__ y, float* __restrict__ seq){
  int idx = blockIdx.x*256 + threadIdx.x;
  if (idx >= L_SEQ*CDIM) return;
  int t = idx / CDIM, c = idx % CDIM;
  int nlo = t - (WIN-1); if (nlo < 0) nlo = 0;
  int nhi = t; if (nhi > NW-1) nhi = NW-1;
  double s = 0.0;
  for (int n = nlo; n <= nhi; ++n)
    s += (double)y[(size_t)(t-n)*M_ROWS + n*CDIM + c];
  seq[idx] = (float)(s / (double)(nhi - nlo + 1));
}

// ---------------- epilogue: 6D -> axis-angle (fp64 math) ----------------
__global__ void k_post(const float* __restrict__ seq, float* __restrict__ out){
  int idx = blockIdx.x*256 + threadIdx.x;
  if (idx >= L_SEQ*24) return;
  int t = idx / 24, j = idx % 24;
  const float* s = seq + t*CDIM + j*6;
  double a1x=(double)s[0], a1y=(double)s[1], a1z=(double)s[2];
  double a2x=(double)s[3], a2y=(double)s[4], a2z=(double)s[5];
  double n1 = sqrt(a1x*a1x + a1y*a1y + a1z*a1z);
  double i1 = 1.0 / fmax(n1, 1e-8);
  double b1x=a1x*i1, b1y=a1y*i1, b1z=a1z*i1;
  double d  = b1x*a2x + b1y*a2y + b1z*a2z;
  double px = a2x - d*b1x, py = a2y - d*b1y, pz = a2z - d*b1z;
  double n2 = sqrt(px*px + py*py + pz*pz);
  double i2 = 1.0 / fmax(n2, 1e-8);
  double b2x=px*i2, b2y=py*i2, b2z=pz*i2;
  double b3x = b1y*b2z - b1z*b2y;
  double b3y = b1z*b2x - b1x*b2z;
  double b3z = b1x*b2y - b1y*b2x;
  double tr = b1x + b2y + b3z;
  double cs = fmin(fmax((tr-1.0)*0.5, -1.0+1e-6), 1.0-1e-6);
  double ang = acos(cs);
  double sn  = sqrt(fmax(1.0 - cs*cs, 1e-12));
  double vx = b3y - b2z, vy = b1z - b3x, vz = b2x - b1y;
  double f = ang / (2.0 * sn);
  float* o = out + t*72 + j*3;
  o[0] = (float)(vx*f); o[1] = (float)(vy*f); o[2] = (float)(vz*f);
}

// ---------------- launcher ----------------
extern "C" void kernel_launch(void* const* d_in, const int* in_sizes, int n_in,
                              void* d_out, int out_size, void* d_ws, size_t ws_size,
                              hipStream_t stream) {
  const float* dp    = (const float*)d_in[0];
  const float* w_in  = (const float*)d_in[1];
  const float* b_in  = (const float*)d_in[2];
  const float* w1a   = (const float*)d_in[3];
  const float* b1a   = (const float*)d_in[4];
  const float* w1b   = (const float*)d_in[5];
  const float* b1b   = (const float*)d_in[6];
  const float* w2a   = (const float*)d_in[7];
  const float* b2a   = (const float*)d_in[8];
  const float* w2b   = (const float*)d_in[9];
  const float* b2b   = (const float*)d_in[10];
  const float* w_out = (const float*)d_in[11];
  const float* b_out = (const float*)d_in[12];
  float* out = (float*)d_out;

  float* d6    = (float*)d_ws;             // 1024*144            = 147456
  float* winP  = d6    + 147456;           // 32*512              = 16384
  float* w1aP  = winP  + 16384;            // 512*256             = 131072
  float* w1bP  = w1aP  + 131072;           // 256*512             = 131072
  float* w2aP  = w1bP  + 131072;
  float* w2bP  = w2aP  + 131072;
  float* woutP = w2bP  + 131072;           // 512*32              = 16384
  float* ybuf  = woutP + 16384;            // 32*993*144          = 4575744
  float* seq   = ybuf  + (size_t)WIN*NW*CDIM; // 147456

  k_prep<<<(L_SEQ*24 + 255)/256, 256, 0, stream>>>(dp, d6);

  k_wprep<<<557056/256, 256, 0, stream>>>(w_in, w1a, w1b, w2a, w2b, w_out,
                                          winP, w1aP, w1bP, w2aP, w2bP, woutP);

  k_mlp<<<NBLK, 256, 0, stream>>>(d6,
      winP, b_in, w1aP, b1a, w1bP, b1b, w2aP, b2a, w2bP, b2b, woutP, b_out,
      ybuf);

  k_scatter<<<(L_SEQ*CDIM + 255)/256, 256, 0, stream>>>(ybuf, seq);
  k_post<<<(L_SEQ*24 + 255)/256, 256, 0, stream>>>(seq, out);
}

// Round 7
// 4700.953 us; speedup vs baseline: 1.0231x; 1.0231x over previous
//
#include <hip/hip_runtime.h>
#include <math.h>

#define L_SEQ 1024
#define WIN   32
#define CDIM  144
#define NW    993            // (1024-32)/1 + 1
#define HDIM  512
#define RDIM  256
#define M_ROWS (NW*CDIM)     // 142992
#define TILE_M 8
#define NBLK  (M_ROWS/TILE_M) // 17874
#define SLOPE 0.1

__device__ __forceinline__ double dlrelu(double x){ return x >= 0.0 ? x : SLOPE*x; }

// ---------------- prologue: axis-angle -> 6D (fp64 math) ----------------
__global__ void k_prep(const float* __restrict__ dp, float* __restrict__ d6){
  int idx = blockIdx.x*256 + threadIdx.x;
  if (idx >= L_SEQ*24) return;
  int l = idx / 24, j = idx % 24;
  const float* a = dp + l*72 + j*3;
  double x = (double)a[0], y = (double)a[1], z = (double)a[2];
  double ang = sqrt(x*x + y*y + z*z);
  double inv = 1.0 / fmax(ang, 1e-8);
  double ax = x*inv, ay = y*inv, az = z*inv;
  double s = sin(ang), c = cos(ang), C = 1.0 - c;
  float* o = d6 + l*CDIM + j*6;
  o[0] = (float)(c + ax*ax*C);
  o[1] = (float)(ax*ay*C - az*s);
  o[2] = (float)(ax*az*C + ay*s);
  o[3] = (float)(ay*ax*C + az*s);
  o[4] = (float)(c + ay*ay*C);
  o[5] = (float)(ay*az*C - ax*s);
}

// ------- weight prep: transpose + pair-interleave + fp64 upconvert -------
// For W[J][K] row-major: dst[k*J + 2*(j%CS) + (j/CS)] = (double)W[j][k].
// A thread owning pair p reads cols (p, p+CS) at k as ONE double2 (b128).
// fp64 upconvert here is exact == the in-kernel cvt it replaces.
__global__ void k_wprep(const float* __restrict__ w_in, const float* __restrict__ w1a,
                        const float* __restrict__ w1b, const float* __restrict__ w2a,
                        const float* __restrict__ w2b, const float* __restrict__ w_out,
                        double* __restrict__ winP, double* __restrict__ w1aP,
                        double* __restrict__ w1bP, double* __restrict__ w2aP,
                        double* __restrict__ w2bP, double* __restrict__ woutP){
  int idx = blockIdx.x*256 + threadIdx.x;
  if (idx < 16384){                                   // w_in (512,32)
    int j = idx >> 5, k = idx & 31;
    winP[k*512 + 2*(j & 255) + (j >> 8)] = (double)w_in[idx];
  } else if (idx < 147456){                           // w1a (256,512)
    int t = idx - 16384; int j = t >> 9, k = t & 511;
    w1aP[k*256 + 2*(j & 127) + (j >> 7)] = (double)w1a[t];
  } else if (idx < 278528){                           // w1b (512,256)
    int t = idx - 147456; int j = t >> 8, k = t & 255;
    w1bP[k*512 + 2*(j & 255) + (j >> 8)] = (double)w1b[t];
  } else if (idx < 409600){                           // w2a (256,512)
    int t = idx - 278528; int j = t >> 9, k = t & 511;
    w2aP[k*256 + 2*(j & 127) + (j >> 7)] = (double)w2a[t];
  } else if (idx < 540672){                           // w2b (512,256)
    int t = idx - 409600; int j = t >> 8, k = t & 255;
    w2bP[k*512 + 2*(j & 255) + (j >> 8)] = (double)w2b[t];
  } else if (idx < 557056){                           // w_out (32,512) -> [k][t]
    int t = idx - 540672; int j = t >> 9, k = t & 511;
    woutP[k*32 + j] = (double)w_out[t];
  }
}

// ---------------- fused MLP ----------------
// Activations fp64 in LDS, [k][r] (r-stride 8) -> per-k act reads are
// wave-uniform broadcast double2 (b128). Weights fp64 pair-interleaved in ws:
// ONE b128 global load per k per thread, zero cvt in the hot loop. Plain
// unrolled loop (R5's manual prefetch regressed -> compiler schedules).
// Numeric chains identical to the passing round-2/4 kernels.
template<int KD, int JD, bool RES>
__device__ __forceinline__ void layerW(const double* S, double* D,
                                       const double* __restrict__ Wp,
                                       const float* __restrict__ bias, int tid){
  constexpr int CS = JD/2;
  constexpr int R  = (JD==512) ? 8 : 4;
  const int p     = (JD==512) ? tid : (tid & 127);
  const int rbase = (JD==512) ? 0   : ((tid >> 7) * 4);
  const double2* wp = (const double2*)Wp + p;   // index k*CS + p

  double acc0[R], acc1[R];
  #pragma unroll
  for (int r = 0; r < R; ++r){ acc0[r]=0.0; acc1[r]=0.0; }

  #pragma unroll 4
  for (int k = 0; k < KD; ++k){
    double2 w = wp[(size_t)k*CS];
    const double* sp = S + k*TILE_M + rbase;
    #pragma unroll
    for (int i = 0; i < R; i += 2){
      double2 v = *(const double2*)(sp + i);
      acc0[i]   = fma(v.x, w.x, acc0[i]);
      acc0[i+1] = fma(v.y, w.x, acc0[i+1]);
      acc1[i]   = fma(v.x, w.y, acc1[i]);
      acc1[i+1] = fma(v.y, w.y, acc1[i+1]);
    }
  }

  double b0 = (double)bias[p], b1 = (double)bias[p + CS];
  double* d0 = D + (size_t)p*TILE_M + rbase;
  double* d1 = D + (size_t)(p+CS)*TILE_M + rbase;
  #pragma unroll
  for (int r = 0; r < R; ++r){
    float v0 = (float)dlrelu(acc0[r] + b0);
    float v1 = (float)dlrelu(acc1[r] + b1);
    if (RES){
      float h0 = (float)d0[r] + v0;   // fp32 residual add (matches reference chain)
      float h1 = (float)d1[r] + v1;
      d0[r] = (double)h0; d1[r] = (double)h1;
    } else {
      d0[r] = (double)v0; d1[r] = (double)v1;
    }
  }
}

__global__ __launch_bounds__(256, 3) void k_mlp(
    const float* __restrict__ d6,
    const double* __restrict__ winP, const float* __restrict__ b_in,
    const double* __restrict__ w1aP, const float* __restrict__ b1a,
    const double* __restrict__ w1bP, const float* __restrict__ b1b,
    const double* __restrict__ w2aP, const float* __restrict__ b2a,
    const double* __restrict__ w2bP, const float* __restrict__ b2b,
    const double* __restrict__ woutP, const float* __restrict__ b_out,
    float* __restrict__ y)
{
  __shared__ __align__(16) double hb[HDIM*TILE_M];   // 32 KiB, [k][r]
  __shared__ __align__(16) double rb[RDIM*TILE_M];   // 16 KiB, [k][r]; xb overlays
  const int tid = threadIdx.x;
  const int m0  = blockIdx.x * TILE_M;

  // gather input windows into xb (= rb[0..255]): xb[t*8 + r] = d6[(n+t)*144 + c]
  {
    int r = tid & 7, t = tid >> 3;       // t in 0..31
    int m = m0 + r;
    int n = m / CDIM, c = m % CDIM;
    rb[t*TILE_M + r] = (double)d6[(n+t)*CDIM + c];
  }
  __syncthreads();

  layerW<WIN , HDIM, false>(rb, hb, winP, b_in, tid);  __syncthreads();
  layerW<HDIM, RDIM, false>(hb, rb, w1aP, b1a, tid);  __syncthreads();
  layerW<RDIM, HDIM, true >(rb, hb, w1bP, b1b, tid);  __syncthreads();
  layerW<HDIM, RDIM, false>(hb, rb, w2aP, b2a, tid);  __syncthreads();
  layerW<RDIM, HDIM, true >(rb, hb, w2bP, b2b, tid);  __syncthreads();

  // ---- L_out: 512 -> 32, one (row, t) per thread; 4 partial fp64 sums ----
  {
    const int r  = tid & 7;
    const int th = tid >> 3;             // 0..31
    const double* wo = woutP + th;       // [k*32 + th]
    double s0=0.0, s1=0.0, s2=0.0, s3=0.0;
    #pragma unroll 2
    for (int k0 = 0; k0 < HDIM; k0 += 4){
      s0 = fma(hb[(k0+0)*TILE_M + r], wo[(k0+0)*32], s0);
      s1 = fma(hb[(k0+1)*TILE_M + r], wo[(k0+1)*32], s1);
      s2 = fma(hb[(k0+2)*TILE_M + r], wo[(k0+2)*32], s2);
      s3 = fma(hb[(k0+3)*TILE_M + r], wo[(k0+3)*32], s3);
    }
    double o = (s0 + s1) + (s2 + s3);
    int m = m0 + r;
    int n = m / CDIM, c = m % CDIM;
    y[(size_t)th*M_ROWS + n*CDIM + c] = (float)(o + (double)b_out[th]);
  }
}

// ---------------- overlap-average scatter (fp64 sum) ----------------
__global__ void k_scatter(const float* __restrict__ y, float* __restrict__ seq){
  int idx = blockIdx.x*256 + threadIdx.x;
  if (idx >= L_SEQ*CDIM) return;
  int t = idx / CDIM, c = idx % CDIM;
  int nlo = t - (WIN-1); if (nlo < 0) nlo = 0;
  int nhi = t; if (nhi > NW-1) nhi = NW-1;
  double s = 0.0;
  for (int n = nlo; n <= nhi; ++n)
    s += (double)y[(size_t)(t-n)*M_ROWS + n*CDIM + c];
  seq[idx] = (float)(s / (double)(nhi - nlo + 1));
}

// ---------------- epilogue: 6D -> axis-angle (fp64 math) ----------------
__global__ void k_post(const float* __restrict__ seq, float* __restrict__ out){
  int idx = blockIdx.x*256 + threadIdx.x;
  if (idx >= L_SEQ*24) return;
  int t = idx / 24, j = idx % 24;
  const float* s = seq + t*CDIM + j*6;
  double a1x=(double)s[0], a1y=(double)s[1], a1z=(double)s[2];
  double a2x=(double)s[3], a2y=(double)s[4], a2z=(double)s[5];
  double n1 = sqrt(a1x*a1x + a1y*a1y + a1z*a1z);
  double i1 = 1.0 / fmax(n1, 1e-8);
  double b1x=a1x*i1, b1y=a1y*i1, b1z=a1z*i1;
  double d  = b1x*a2x + b1y*a2y + b1z*a2z;
  double px = a2x - d*b1x, py = a2y - d*b1y, pz = a2z - d*b1z;
  double n2 = sqrt(px*px + py*py + pz*pz);
  double i2 = 1.0 / fmax(n2, 1e-8);
  double b2x=px*i2, b2y=py*i2, b2z=pz*i2;
  double b3x = b1y*b2z - b1z*b2y;
  double b3y = b1z*b2x - b1x*b2z;
  double b3z = b1x*b2y - b1y*b2x;
  double tr = b1x + b2y + b3z;
  double cs = fmin(fmax((tr-1.0)*0.5, -1.0+1e-6), 1.0-1e-6);
  double ang = acos(cs);
  double sn  = sqrt(fmax(1.0 - cs*cs, 1e-12));
  double vx = b3y - b2z, vy = b1z - b3x, vz = b2x - b1y;
  double f = ang / (2.0 * sn);
  float* o = out + t*72 + j*3;
  o[0] = (float)(vx*f); o[1] = (float)(vy*f); o[2] = (float)(vz*f);
}

// ---------------- launcher ----------------
extern "C" void kernel_launch(void* const* d_in, const int* in_sizes, int n_in,
                              void* d_out, int out_size, void* d_ws, size_t ws_size,
                              hipStream_t stream) {
  const float* dp    = (const float*)d_in[0];
  const float* w_in  = (const float*)d_in[1];
  const float* b_in  = (const float*)d_in[2];
  const float* w1a   = (const float*)d_in[3];
  const float* b1a   = (const float*)d_in[4];
  const float* w1b   = (const float*)d_in[5];
  const float* b1b   = (const float*)d_in[6];
  const float* w2a   = (const float*)d_in[7];
  const float* b2a   = (const float*)d_in[8];
  const float* w2b   = (const float*)d_in[9];
  const float* b2b   = (const float*)d_in[10];
  const float* w_out = (const float*)d_in[11];
  const float* b_out = (const float*)d_in[12];
  float* out = (float*)d_out;

  // ws layout: fp64 weight arrays first (8B-aligned), then fp32 buffers.
  double* winP  = (double*)d_ws;           // 32*512   = 16384 doubles
  double* w1aP  = winP  + 16384;           // 512*256  = 131072
  double* w1bP  = w1aP  + 131072;          // 256*512  = 131072
  double* w2aP  = w1bP  + 131072;
  double* w2bP  = w2aP  + 131072;
  double* woutP = w2bP  + 131072;          // 512*32   = 16384
  float*  d6    = (float*)(woutP + 16384); // 1024*144 = 147456 floats
  float*  ybuf  = d6 + 147456;             // 32*993*144 = 4575744
  float*  seq   = ybuf + (size_t)WIN*NW*CDIM; // 147456

  k_prep<<<(L_SEQ*24 + 255)/256, 256, 0, stream>>>(dp, d6);

  k_wprep<<<557056/256, 256, 0, stream>>>(w_in, w1a, w1b, w2a, w2b, w_out,
                                          winP, w1aP, w1bP, w2aP, w2bP, woutP);

  k_mlp<<<NBLK, 256, 0, stream>>>(d6,
      winP, b_in, w1aP, b1a, w1bP, b1b, w2aP, b2a, w2bP, b2b, woutP, b_out,
      ybuf);

  k_scatter<<<(L_SEQ*CDIM + 255)/256, 256, 0, stream>>>(ybuf, seq);
  k_post<<<(L_SEQ*24 + 255)/256, 256, 0, stream>>>(seq, out);
}

// Round 8
// 2656.816 us; speedup vs baseline: 1.8103x; 1.7694x over previous
//
#include <hip/hip_runtime.h>
#include <math.h>

#define L_SEQ 1024
#define WIN   32
#define CDIM  144
#define NW    993            // (1024-32)/1 + 1
#define HDIM  512
#define RDIM  256
#define M_ROWS (NW*CDIM)     // 142992
#define TILE_M 16
#define NBLK  (M_ROWS/TILE_M) // 8937
#define SLOPE 0.1

typedef double dx4 __attribute__((ext_vector_type(4)));

__device__ __forceinline__ double dlrelu(double x){ return x >= 0.0 ? x : SLOPE*x; }

// ---------------- prologue: axis-angle -> 6D (fp64 math) ----------------
__global__ void k_prep(const float* __restrict__ dp, float* __restrict__ d6){
  int idx = blockIdx.x*256 + threadIdx.x;
  if (idx >= L_SEQ*24) return;
  int l = idx / 24, j = idx % 24;
  const float* a = dp + l*72 + j*3;
  double x = (double)a[0], y = (double)a[1], z = (double)a[2];
  double ang = sqrt(x*x + y*y + z*z);
  double inv = 1.0 / fmax(ang, 1e-8);
  double ax = x*inv, ay = y*inv, az = z*inv;
  double s = sin(ang), c = cos(ang), C = 1.0 - c;
  float* o = d6 + l*CDIM + j*6;
  o[0] = (float)(c + ax*ax*C);
  o[1] = (float)(ax*ay*C - az*s);
  o[2] = (float)(ax*az*C + ay*s);
  o[3] = (float)(ay*ax*C + az*s);
  o[4] = (float)(c + ay*ay*C);
  o[5] = (float)(ay*az*C - ax*s);
}

// ---------------- weight transpose (fp32, k-major) ----------------
// dst[k*R + j] = src[j*C + k]  (R = #cols of src = out-dim, C = k-dim)
__global__ void k_transpose(const float* __restrict__ src, float* __restrict__ dst,
                            int R, int C){
  int idx = blockIdx.x*256 + threadIdx.x;
  if (idx >= R*C) return;
  int r = idx / C, c = idx % C;
  dst[c*R + r] = src[idx];
}

// ---------------- fused MLP via fp64 MFMA ----------------
// Activations fp32 in LDS, layout [k][16] (addr k*16 + r) — A-operand reads
// are contiguous 64-float wave reads (conflict-free). Weights fp32 k-major
// in ws (L2-resident, 2.2 MB total). Per 16x16x4 MFMA:
//   A: lane(row=l&15, k=l>>4) one double;  B: lane(col=l&15, k=l>>4);
//   D: col=l&15, row=4*(l>>4)+i  (i = vector elem 0..3).
// fp64 accumulation == exact vs reference; activations rounded through fp32
// at each store; residual adds in fp32 (same chains as passing rounds).
template<int KD, int JD, bool RES>
__device__ __forceinline__ void layer_mfma(const float* S, float* Dst,
                                           const float* __restrict__ Wt,
                                           const float* __restrict__ bias,
                                           int wave, int lr, int lk){
  constexpr int NT = JD / 64;          // col-tiles (16 cols each) per wave
  dx4 acc[NT];
  #pragma unroll
  for (int t = 0; t < NT; ++t) acc[t] = (dx4){0.0, 0.0, 0.0, 0.0};

  const int colbase = wave * (NT*16);
  for (int k0 = 0; k0 < KD; k0 += 4){
    double a = (double)S[(k0 + lk)*16 + lr];
    const float* wrow = Wt + (size_t)(k0 + lk)*JD + colbase + lr;
    #pragma unroll
    for (int t = 0; t < NT; ++t){
      double b = (double)wrow[t*16];
      acc[t] = __builtin_amdgcn_mfma_f64_16x16x4f64(a, b, acc[t], 0, 0, 0);
    }
  }

  #pragma unroll
  for (int t = 0; t < NT; ++t){
    int j = colbase + t*16 + lr;
    double bj = (double)bias[j];
    #pragma unroll
    for (int i = 0; i < 4; ++i){
      int r = 4*lk + i;
      float v = (float)dlrelu(acc[t][i] + bj);
      float* dp = Dst + j*16 + r;
      if (RES) *dp = *dp + v;          // fp32 residual add (reference chain)
      else     *dp = v;
    }
  }
}

__global__ __launch_bounds__(256, 3) void k_mlp(
    const float* __restrict__ d6,
    const float* __restrict__ winT, const float* __restrict__ b_in,
    const float* __restrict__ w1aT, const float* __restrict__ b1a,
    const float* __restrict__ w1bT, const float* __restrict__ b1b,
    const float* __restrict__ w2aT, const float* __restrict__ b2a,
    const float* __restrict__ w2bT, const float* __restrict__ b2b,
    const float* __restrict__ woutT, const float* __restrict__ b_out,
    float* __restrict__ y)
{
  __shared__ __align__(16) float hb[HDIM*16];   // 32 KiB, [k][r]
  __shared__ __align__(16) float rb[RDIM*16];   // 16 KiB, [k][r]; xb + L_out partials overlay
  const int tid  = threadIdx.x;
  const int wave = tid >> 6;
  const int lane = tid & 63;
  const int lr   = lane & 15;          // A-row / B-col / D-col
  const int lk   = lane >> 4;          // k within 4 / D row-group
  const int m0   = blockIdx.x * TILE_M;

  // gather input windows into xb (= rb): xb[t*16 + r] = d6[(n+t)*144 + c]
  for (int idx = tid; idx < WIN*16; idx += 256){
    int r = idx & 15, t = idx >> 4;
    int m = m0 + r;
    int n = m / CDIM, c = m % CDIM;
    rb[t*16 + r] = d6[(n+t)*CDIM + c];
  }
  __syncthreads();

  layer_mfma<WIN , HDIM, false>(rb, hb, winT, b_in, wave, lr, lk); __syncthreads();
  layer_mfma<HDIM, RDIM, false>(hb, rb, w1aT, b1a, wave, lr, lk); __syncthreads();
  layer_mfma<RDIM, HDIM, true >(rb, hb, w1bT, b1b, wave, lr, lk); __syncthreads();
  layer_mfma<HDIM, RDIM, false>(hb, rb, w2aT, b2a, wave, lr, lk); __syncthreads();
  layer_mfma<RDIM, HDIM, true >(rb, hb, w2bT, b2b, wave, lr, lk); __syncthreads();

  // ---- L_out: 512 -> 32, k-split across waves + fp64 LDS reduction ----
  {
    dx4 acc0 = (dx4){0.0,0.0,0.0,0.0};
    dx4 acc1 = (dx4){0.0,0.0,0.0,0.0};
    const int kbase = wave * 128;
    for (int k0 = kbase; k0 < kbase + 128; k0 += 4){
      double a = (double)hb[(k0 + lk)*16 + lr];
      const float* wrow = woutT + (size_t)(k0 + lk)*32 + lr;
      acc0 = __builtin_amdgcn_mfma_f64_16x16x4f64(a, (double)wrow[0],  acc0, 0,0,0);
      acc1 = __builtin_amdgcn_mfma_f64_16x16x4f64(a, (double)wrow[16], acc1, 0,0,0);
    }
    double* part = (double*)rb;        // 4 waves x 2 tiles x [row*16+col] = 2048 doubles
    #pragma unroll
    for (int i = 0; i < 4; ++i){
      part[wave*512 +   0 + (4*lk + i)*16 + lr] = acc0[i];
      part[wave*512 + 256 + (4*lk + i)*16 + lr] = acc1[i];
    }
    __syncthreads();
    for (int o = tid; o < 512; o += 256){
      int j = o >> 4, r = o & 15;
      int off = (j >> 4)*256 + r*16 + (j & 15);
      double s = (part[off] + part[512 + off]) + (part[1024 + off] + part[1536 + off]);
      int m = m0 + r;
      int n = m / CDIM, c = m % CDIM;
      y[(size_t)j*M_ROWS + n*CDIM + c] = (float)(s + (double)b_out[j]);
    }
  }
}

// ---------------- overlap-average scatter (fp64 sum) ----------------
__global__ void k_scatter(const float* __restrict__ y, float* __restrict__ seq){
  int idx = blockIdx.x*256 + threadIdx.x;
  if (idx >= L_SEQ*CDIM) return;
  int t = idx / CDIM, c = idx % CDIM;
  int nlo = t - (WIN-1); if (nlo < 0) nlo = 0;
  int nhi = t; if (nhi > NW-1) nhi = NW-1;
  double s = 0.0;
  for (int n = nlo; n <= nhi; ++n)
    s += (double)y[(size_t)(t-n)*M_ROWS + n*CDIM + c];
  seq[idx] = (float)(s / (double)(nhi - nlo + 1));
}

// ---------------- epilogue: 6D -> axis-angle (fp64 math) ----------------
__global__ void k_post(const float* __restrict__ seq, float* __restrict__ out){
  int idx = blockIdx.x*256 + threadIdx.x;
  if (idx >= L_SEQ*24) return;
  int t = idx / 24, j = idx % 24;
  const float* s = seq + t*CDIM + j*6;
  double a1x=(double)s[0], a1y=(double)s[1], a1z=(double)s[2];
  double a2x=(double)s[3], a2y=(double)s[4], a2z=(double)s[5];
  double n1 = sqrt(a1x*a1x + a1y*a1y + a1z*a1z);
  double i1 = 1.0 / fmax(n1, 1e-8);
  double b1x=a1x*i1, b1y=a1y*i1, b1z=a1z*i1;
  double d  = b1x*a2x + b1y*a2y + b1z*a2z;
  double px = a2x - d*b1x, py = a2y - d*b1y, pz = a2z - d*b1z;
  double n2 = sqrt(px*px + py*py + pz*pz);
  double i2 = 1.0 / fmax(n2, 1e-8);
  double b2x=px*i2, b2y=py*i2, b2z=pz*i2;
  double b3x = b1y*b2z - b1z*b2y;
  double b3y = b1z*b2x - b1x*b2z;
  double b3z = b1x*b2y - b1y*b2x;
  double tr = b1x + b2y + b3z;
  double cs = fmin(fmax((tr-1.0)*0.5, -1.0+1e-6), 1.0-1e-6);
  double ang = acos(cs);
  double sn  = sqrt(fmax(1.0 - cs*cs, 1e-12));
  double vx = b3y - b2z, vy = b1z - b3x, vz = b2x - b1y;
  double f = ang / (2.0 * sn);
  float* o = out + t*72 + j*3;
  o[0] = (float)(vx*f); o[1] = (float)(vy*f); o[2] = (float)(vz*f);
}

// ---------------- launcher ----------------
extern "C" void kernel_launch(void* const* d_in, const int* in_sizes, int n_in,
                              void* d_out, int out_size, void* d_ws, size_t ws_size,
                              hipStream_t stream) {
  const float* dp    = (const float*)d_in[0];
  const float* w_in  = (const float*)d_in[1];
  const float* b_in  = (const float*)d_in[2];
  const float* w1a   = (const float*)d_in[3];
  const float* b1a   = (const float*)d_in[4];
  const float* w1b   = (const float*)d_in[5];
  const float* b1b   = (const float*)d_in[6];
  const float* w2a   = (const float*)d_in[7];
  const float* b2a   = (const float*)d_in[8];
  const float* w2b   = (const float*)d_in[9];
  const float* b2b   = (const float*)d_in[10];
  const float* w_out = (const float*)d_in[11];
  const float* b_out = (const float*)d_in[12];
  float* out = (float*)d_out;

  float* d6    = (float*)d_ws;             // 1024*144            = 147456
  float* winT  = d6    + 147456;           // 32*512              = 16384
  float* w1aT  = winT  + 16384;            // 512*256             = 131072
  float* w1bT  = w1aT  + 131072;           // 256*512             = 131072
  float* w2aT  = w1bT  + 131072;
  float* w2bT  = w2aT  + 131072;
  float* woutT = w2bT  + 131072;           // 512*32              = 16384
  float* ybuf  = woutT + 16384;            // 32*993*144          = 4575744
  float* seq   = ybuf  + (size_t)WIN*NW*CDIM; // 147456

  k_prep<<<(L_SEQ*24 + 255)/256, 256, 0, stream>>>(dp, d6);

  k_transpose<<<(512*32  + 255)/256, 256, 0, stream>>>(w_in,  winT,  512, 32);
  k_transpose<<<(256*512 + 255)/256, 256, 0, stream>>>(w1a,   w1aT,  256, 512);
  k_transpose<<<(512*256 + 255)/256, 256, 0, stream>>>(w1b,   w1bT,  512, 256);
  k_transpose<<<(256*512 + 255)/256, 256, 0, stream>>>(w2a,   w2aT,  256, 512);
  k_transpose<<<(512*256 + 255)/256, 256, 0, stream>>>(w2b,   w2bT,  512, 256);
  k_transpose<<<(32*512  + 255)/256, 256, 0, stream>>>(w_out, woutT, 32, 512);

  k_mlp<<<NBLK, 256, 0, stream>>>(d6,
      winT, b_in, w1aT, b1a, w1bT, b1b, w2aT, b2a, w2bT, b2b, woutT, b_out,
      ybuf);

  k_scatter<<<(L_SEQ*CDIM + 255)/256, 256, 0, stream>>>(ybuf, seq);
  k_post<<<(L_SEQ*24 + 255)/256, 256, 0, stream>>>(seq, out);
}